// Round 10
// baseline (206.197 us; speedup 1.0000x reference)
//
#include <hip/hip_runtime.h>
#include <math.h>

#define N_EMBED 8192
#define DIM 32
#define NQ 32768              // 32*32*32 queries

#define QPB 256               // queries per block (4 waves x 64)
#define NQG (NQ / QPB)        // 128 query groups
#define KSPL 8
#define KCHUNK (N_EMBED / KSPL)   // 1024 codes per block
#define TILE 128              // codes per LDS tile
#define NTILES (KCHUNK / TILE)    // 8
#define NPLANE 8              // p = s*4 + part ; s=0: h, s=1: m' = (x-h)*4096
#define LSTRIDE 130           // chunks per plane in LDS (+2 pad)

#define LOSS_OFF  1048576
#define ENT_OFF   1048577
#define IDX_OFF   1048578

typedef __attribute__((ext_vector_type(8))) _Float16 half8;
typedef __attribute__((ext_vector_type(4))) float floatx4;

// ---------------------------------------------------------------------------
// K0: prep. One thread per code: normalize + exact 2-way fp16 split
// (h=fp16(x), m'=fp16((x-h)*4096), scaled 2^12 to stay fp16-normal),
// plane-major: plane p = s*4+part, chunk = p*8192+k (16 B). Zeroes usage,
// per-qg counters, global counter, loss. Separate kernel ON PURPOSE (R7:
// inlining the split into score staging cost MfmaUtil).
// ---------------------------------------------------------------------------
__global__ __launch_bounds__(256) void prep_kernel(const float* __restrict__ e,
                                                   half8* __restrict__ esplit,
                                                   unsigned* __restrict__ usage,
                                                   unsigned* __restrict__ qg_ctr,
                                                   float* __restrict__ loss_acc,
                                                   unsigned* __restrict__ fin_ctr) {
    int k = blockIdx.x * 256 + threadIdx.x;    // 0..8191
    const float4* src = (const float4*)(e + k * DIM);
    float v[DIM];
    float ss = 0.f;
#pragma unroll
    for (int i = 0; i < 8; ++i) {
        float4 t = src[i];
        v[i*4+0] = t.x; v[i*4+1] = t.y; v[i*4+2] = t.z; v[i*4+3] = t.w;
        ss += t.x*t.x + t.y*t.y + t.z*t.z + t.w*t.w;
    }
    float inv = 1.f / fmaxf(sqrtf(ss), 1e-12f);
    usage[k] = 0u;
    if (k < NQG) qg_ctr[k] = 0u;
    if (k == 0) { loss_acc[0] = 0.f; fin_ctr[0] = 0u; }

#pragma unroll
    for (int part = 0; part < 4; ++part) {
        half8 h8, m8;
#pragma unroll
        for (int j = 0; j < 8; ++j) {
            float xx = v[part * 8 + j] * inv;
            _Float16 h = (_Float16)xx;                          // RNE
            _Float16 m = (_Float16)((xx - (float)h) * 4096.0f); // exact residual
            h8[j] = h; m8[j] = m;
        }
        esplit[(0 * 4 + part) * N_EMBED + k] = h8;
        esplit[(1 * 4 + part) * N_EMBED + k] = m8;
    }
}

// ---------------------------------------------------------------------------
// K1: R5's measured-best scorer (66 us: 256 thr / 4 waves, KSPL=8, TILE=128
// double-buffered, 16x16x32 3-term split-fp16) + FUSED finalize:
//  - per-qg last-done block (of the 8 kc-blocks) finalizes its 256 queries,
//    overlapping other query groups' score blocks (was a separate kernel at
//    2 waves/CU, serially after score);
//  - global last-done block computes entropy + loss scalars.
// Cross-XCD safety: keys8 written/read with agent-scope atomics; counters via
// __threadfence + acq-rel RMW (the pattern R5-R9's done_ctr validated).
// No spinning anywhere -> no deadlock regardless of dispatch order.
// ---------------------------------------------------------------------------
__global__ __launch_bounds__(256, 4) void score_kernel(const float* __restrict__ z,
                                                       const float* __restrict__ e,
                                                       const half8* __restrict__ esplit,
                                                       unsigned long long* __restrict__ keys8,
                                                       unsigned* __restrict__ usage,
                                                       unsigned* __restrict__ qg_ctr,
                                                       float* __restrict__ loss_acc,
                                                       unsigned* __restrict__ fin_ctr,
                                                       float* __restrict__ out) {
    __shared__ half8 lds[2][NPLANE * LSTRIDE];   // 33,280 B
    __shared__ double sm[256];                   // entropy tail scratch
    __shared__ unsigned qflag, eflag;

    const int t = threadIdx.x;
    const int lane = t & 63;
    const int w = t >> 6;            // wave 0..3
    const int quad = lane >> 4;      // k-group / C-row group
    const int lc = lane & 15;        // A-row / B-col / C-col
    const int qg = blockIdx.x & (NQG - 1);
    const int kc = blockIdx.x >> 7;          // 0..KSPL-1
    const int kbase = kc * KCHUNK;
    const int qbase = qg * QPB + w * 64;

    // ---- A fragments: 4 q-tiles, on-the-fly normalize + fp16 split ----
    half8 ah[4], am[4];
#pragma unroll
    for (int qt = 0; qt < 4; ++qt) {
        int q = qbase + qt * 16 + lc;
        const float* zp = z + (q >> 10) * (DIM * 1024) + (q & 1023);
        float x[8];
        float ss = 0.f;
#pragma unroll
        for (int j = 0; j < 8; ++j) {
            x[j] = zp[(quad * 8 + j) * 1024];
            ss = fmaf(x[j], x[j], ss);
        }
        ss += __shfl_xor(ss, 16, 64);   // combine the 4 quads holding this query
        ss += __shfl_xor(ss, 32, 64);
        float inv = 1.f / fmaxf(sqrtf(ss), 1e-12f);
#pragma unroll
        for (int j = 0; j < 8; ++j) {
            float xx = x[j] * inv;
            _Float16 h = (_Float16)xx;
            _Float16 m = (_Float16)((xx - (float)h) * 4096.0f);
            ah[qt][j] = h; am[qt][j] = m;
        }
    }

    float best[16];
    int bk[16];
#pragma unroll
    for (int i = 0; i < 16; ++i) { best[i] = -2.0f; bk[i] = 0; }

    const floatx4 z4 = {0.f, 0.f, 0.f, 0.f};

    // ---- staging: 8 planes x 128 chunks = 1024 chunks / 256 threads = 4 ea ----
#pragma unroll
    for (int j = 0; j < 4; ++j) {
        int c = t + j * 256; int p = c >> 7, i = c & 127;
        lds[0][p * LSTRIDE + i] = esplit[p * N_EMBED + kbase + i];
    }
    __syncthreads();

    for (int kt = 0; kt < NTILES; ++kt) {
        half8 st[4];
        if (kt + 1 < NTILES) {
#pragma unroll
            for (int j = 0; j < 4; ++j) {
                int c = t + j * 256; int p = c >> 7, i = c & 127;
                st[j] = esplit[p * N_EMBED + kbase + (kt + 1) * TILE + i];
            }
        }
        const half8* __restrict__ buf = lds[kt & 1];
#pragma unroll 2
        for (int ct = 0; ct < TILE / 16; ++ct) {
            half8 bh = buf[(0 * 4 + quad) * LSTRIDE + ct * 16 + lc];
            half8 bm = buf[(1 * 4 + quad) * LSTRIDE + ct * 16 + lc];
            const int kk = kbase + kt * TILE + ct * 16 + lc;
#pragma unroll
            for (int qt = 0; qt < 4; ++qt) {
                floatx4 a0 = __builtin_amdgcn_mfma_f32_16x16x32_f16(ah[qt], bh, z4, 0, 0, 0);
                floatx4 a1 = __builtin_amdgcn_mfma_f32_16x16x32_f16(ah[qt], bm, z4, 0, 0, 0);
                a1 = __builtin_amdgcn_mfma_f32_16x16x32_f16(am[qt], bh, a1, 0, 0, 0);
#pragma unroll
                for (int r = 0; r < 4; ++r) {
                    float d = fmaf(a1[r], 0x1p-12f, a0[r]);
                    if (d > best[qt * 4 + r]) { best[qt * 4 + r] = d; bk[qt * 4 + r] = kk; }
                }
            }
        }
        __syncthreads();
        if (kt + 1 < NTILES) {
#pragma unroll
            for (int j = 0; j < 4; ++j) {
                int c = t + j * 256; int p = c >> 7, i = c & 127;
                lds[(kt + 1) & 1][p * LSTRIDE + i] = st[j];
            }
            __syncthreads();
        }
    }

    // ---- epilogue: pack (dot,k), reduce over 16 cols, agent-store per row ----
#pragma unroll
    for (int i = 0; i < 16; ++i) {
        unsigned ub = __float_as_uint(best[i]);
        ub = (ub & 0x80000000u) ? ~ub : (ub | 0x80000000u);
        unsigned long long key = ((unsigned long long)ub << 32) | (unsigned)(~bk[i]);
#pragma unroll
        for (int msk = 1; msk <= 8; msk <<= 1) {
            unsigned long long o = __shfl_xor(key, msk, 64);
            key = (o > key) ? o : key;
        }
        if (lc == 0) {
            int qt = i >> 2, r = i & 3;
            int q = qbase + qt * 16 + quad * 4 + r;   // C row = quad*4 + reg
            __hip_atomic_store(&keys8[kc * NQ + q], key, __ATOMIC_RELAXED,
                               __HIP_MEMORY_SCOPE_AGENT);   // coherent cross-XCD
        }
    }

    // ---- per-qg last-done block runs the fused finalize ----
    __threadfence();                 // release our key stores device-wide
    __syncthreads();
    if (t == 0) {
        unsigned prev = __hip_atomic_fetch_add(&qg_ctr[qg], 1u, __ATOMIC_ACQ_REL,
                                               __HIP_MEMORY_SCOPE_AGENT);
        qflag = (prev == KSPL - 1) ? 1u : 0u;
    }
    __syncthreads();

    if (qflag) {
        int n = qg * QPB + t;            // this block finalizes its 256 queries
        int b  = n >> 10;
        int hw = n & 1023;
        const float* zb = z + b * (DIM * 1024) + hw;

        float q[DIM];
        float ss = 0.f;
#pragma unroll
        for (int d = 0; d < DIM; ++d) {
            q[d] = zb[d * 1024];
            ss = fmaf(q[d], q[d], ss);
        }
        float inv = 1.f / fmaxf(sqrtf(ss), 1e-12f);
#pragma unroll
        for (int d = 0; d < DIM; ++d) q[d] *= inv;

        unsigned long long bestkey = 0ull;
#pragma unroll
        for (int c = 0; c < KSPL; ++c) {
            unsigned long long kk = __hip_atomic_load(&keys8[c * NQ + n],
                                                      __ATOMIC_RELAXED,
                                                      __HIP_MEMORY_SCOPE_AGENT);
            bestkey = (kk > bestkey) ? kk : bestkey;
        }
        int idx = (int)(~(unsigned)(bestkey & 0xFFFFFFFFull));

        atomicAdd(&usage[idx], 1u);

        float wv[DIM];
        float ss2 = 0.f;
        const float4* er = (const float4*)(e + idx * DIM);
#pragma unroll
        for (int d8 = 0; d8 < 8; ++d8) {
            float4 t4 = er[d8];
            wv[d8*4+0] = t4.x; wv[d8*4+1] = t4.y; wv[d8*4+2] = t4.z; wv[d8*4+3] = t4.w;
            ss2 += t4.x*t4.x + t4.y*t4.y + t4.z*t4.z + t4.w*t4.w;
        }
        float inv2 = 1.f / fmaxf(sqrtf(ss2), 1e-12f);

        float lsum = 0.f;
        float* outb = out + b * (DIM * 1024) + hw;
#pragma unroll
        for (int d = 0; d < DIM; ++d) {
            float zq = wv[d] * inv2;
            float diff = zq - q[d];
            lsum = fmaf(diff, diff, lsum);
            outb[d * 1024] = q[d] + (zq - q[d]);   // faithful to zn + sg(z_q - zn)
        }
        out[IDX_OFF + n] = (float)idx;

#pragma unroll
        for (int off = 32; off > 0; off >>= 1)
            lsum += __shfl_down(lsum, off, 64);
        if ((t & 63) == 0)
            atomicAdd(loss_acc, lsum);

        // ---- global last-done finalizer computes the scalars ----
        __threadfence();
        __syncthreads();
        if (t == 0) {
            unsigned prev = __hip_atomic_fetch_add(fin_ctr, 1u, __ATOMIC_ACQ_REL,
                                                   __HIP_MEMORY_SCOPE_AGENT);
            eflag = (prev == NQG - 1) ? 1u : 0u;
        }
        __syncthreads();
        if (eflag) {
            double local = 0.0;
            const float denom = 32768.8192f;   // sum(usage)+K*eps; sum(usage)==NQ
            for (int k = t; k < N_EMBED; k += 256) {
                unsigned c = __hip_atomic_load(&usage[k], __ATOMIC_RELAXED,
                                               __HIP_MEMORY_SCOPE_AGENT);
                float p = ((float)c + 1e-4f) / denom;
                local += (double)(-(p * logf(p)));
            }
            sm[t] = local;
            __syncthreads();
            for (int s = 128; s > 0; s >>= 1) {
                if (t < s) sm[t] += sm[t + s];
                __syncthreads();
            }
            if (t == 0) {
                float la = __hip_atomic_load(loss_acc, __ATOMIC_RELAXED,
                                             __HIP_MEMORY_SCOPE_AGENT);
                out[LOSS_OFF] = (float)(1.25 * (double)la / 32768.0);  // (beta+1)*mean
                out[ENT_OFF]  = (float)sm[0];
            }
        }
    }
}

// ---------------------------------------------------------------------------
extern "C" void kernel_launch(void* const* d_in, const int* in_sizes, int n_in,
                              void* d_out, int out_size, void* d_ws, size_t ws_size,
                              hipStream_t stream) {
    const float* z   = (const float*)d_in[0];   // (32, 32, 32, 32) bchw
    const float* emb = (const float*)d_in[1];   // (8192, 32)
    float* out = (float*)d_out;

    char* ws = (char*)d_ws;
    half8* esplit             = (half8*)ws;                                  // 1 MiB @ 0
    unsigned long long* keys8 = (unsigned long long*)(ws + (1 << 20));       // 2 MiB
    unsigned* usage           = (unsigned*)(ws + (3 << 20));                 // 32 KiB
    unsigned* qg_ctr          = (unsigned*)(ws + (3 << 20) + 32768);         // 512 B
    float* loss_acc           = (float*)(ws + (3 << 20) + 32768 + 512);
    unsigned* fin_ctr         = (unsigned*)(ws + (3 << 20) + 32768 + 512 + 4);

    prep_kernel<<<N_EMBED / 256, 256, 0, stream>>>(emb, esplit, usage, qg_ctr,
                                                   loss_acc, fin_ctr);
    score_kernel<<<NQG * KSPL, 256, 0, stream>>>(z, emb, esplit, keys8, usage,
                                                 qg_ctr, loss_acc, fin_ctr, out);
}

// Round 11
// 145.797 us; speedup vs baseline: 1.4143x; 1.4143x over previous
//
#include <hip/hip_runtime.h>
#include <math.h>

#define N_EMBED 8192
#define DIM 32
#define NQ 32768              // 32*32*32 queries

#define QPB 512               // queries per block (8 waves x 64)
#define NQG (NQ / QPB)        // 64 query groups
#define KSPL 16
#define KCHUNK (N_EMBED / KSPL)   // 512 codes per block, staged ONCE (64 KB)
#define NCT (KCHUNK / 16)         // 32 MFMA column-tiles

#define LOSS_OFF  1048576
#define ENT_OFF   1048577
#define IDX_OFF   1048578

typedef __attribute__((ext_vector_type(8))) _Float16 half8;
typedef __attribute__((ext_vector_type(4))) float floatx4;

// ---------------------------------------------------------------------------
// K1: split-fp16 MFMA scorer, 16x16x32, 3 terms: dot = hh + 2^-12(hm' + m'h)
// (h=fp16(x), m'=fp16((x-h)*4096) -- exact residual, scaled 2^12 to stay
// fp16-normal; error ~1e-8 rms << typical top-gap 1.5e-2).
// Structure = best-of-measured hybrid:
//  - 2 dispatches (R7: each dispatch costs ~7 us; no prep kernel);
//  - single-shot 64 KB stage + ONE barrier (R8: 72 us score, 0 bank conflicts);
//  - split computed ONCE per block at staging, 1 thread = 1 code (unlike R7's
//    per-tile split bursts inside the MFMA loop, which cost MfmaUtil 32->29).
// Block 0 zeroes usage/loss/done for finalize (stream-ordered after us).
// Top-1 per (query, chunk) -> keys16[kc*NQ + q], plain store (block owns slot).
// ---------------------------------------------------------------------------
__global__ __launch_bounds__(512, 2) void score_kernel(const float* __restrict__ z,
                                                       const float* __restrict__ e,
                                                       unsigned long long* __restrict__ keys16,
                                                       unsigned* __restrict__ usage,
                                                       float* __restrict__ loss_acc,
                                                       unsigned* __restrict__ done_ctr) {
    __shared__ half8 lds[8 * KCHUNK];   // 64 KB: plane p * 512 + code

    const int t = threadIdx.x;

    if (blockIdx.x == 0) {           // zero side accumulators for finalize
        for (int i = t; i < N_EMBED; i += 512) usage[i] = 0u;
        if (t == 0) { loss_acc[0] = 0.f; done_ctr[0] = 0u; }
    }

    const int lane = t & 63;
    const int w = t >> 6;            // wave 0..7
    const int quad = lane >> 4;      // k-group / C-row group
    const int lc = lane & 15;        // A-row / B-col / C-col
    const int qg = blockIdx.x & (NQG - 1);
    const int kc = blockIdx.x >> 6;          // 0..KSPL-1
    const int kbase = kc * KCHUNK;
    const int qbase = qg * QPB + w * 64;

    // ---- one-time stage + split: thread t owns code kbase+t ----
    {
        const float4* src = (const float4*)(e + (kbase + t) * DIM);
        float v[DIM];
        float ss = 0.f;
#pragma unroll
        for (int i = 0; i < 8; ++i) {
            float4 f4 = src[i];
            v[i*4+0] = f4.x; v[i*4+1] = f4.y; v[i*4+2] = f4.z; v[i*4+3] = f4.w;
            ss += f4.x*f4.x + f4.y*f4.y + f4.z*f4.z + f4.w*f4.w;
        }
        float inv = 1.f / fmaxf(sqrtf(ss), 1e-12f);
#pragma unroll
        for (int part = 0; part < 4; ++part) {
            half8 h8, m8;
#pragma unroll
            for (int j = 0; j < 8; ++j) {
                float xx = v[part * 8 + j] * inv;
                _Float16 h = (_Float16)xx;                          // RNE
                _Float16 m = (_Float16)((xx - (float)h) * 4096.0f); // exact residual
                h8[j] = h; m8[j] = m;
            }
            lds[(0 * 4 + part) * KCHUNK + t] = h8;   // consecutive t -> consecutive 16B
            lds[(1 * 4 + part) * KCHUNK + t] = m8;
        }
    }

    // ---- A fragments: 4 q-tiles of 16 rows, normalize + fp16 split ----
    half8 ah[4], am[4];
#pragma unroll
    for (int qt = 0; qt < 4; ++qt) {
        int q = qbase + qt * 16 + lc;
        const float* zp = z + (q >> 10) * (DIM * 1024) + (q & 1023);
        float x[8];
        float ss = 0.f;
#pragma unroll
        for (int j = 0; j < 8; ++j) {
            x[j] = zp[(quad * 8 + j) * 1024];
            ss = fmaf(x[j], x[j], ss);
        }
        ss += __shfl_xor(ss, 16, 64);   // combine the 4 quads holding this query
        ss += __shfl_xor(ss, 32, 64);
        float inv = 1.f / fmaxf(sqrtf(ss), 1e-12f);
#pragma unroll
        for (int j = 0; j < 8; ++j) {
            float xx = x[j] * inv;
            _Float16 h = (_Float16)xx;
            _Float16 m = (_Float16)((xx - (float)h) * 4096.0f);
            ah[qt][j] = h; am[qt][j] = m;
        }
    }

    float best[16];
    int bk[16];
#pragma unroll
    for (int i = 0; i < 16; ++i) { best[i] = -2.0f; bk[i] = 0; }

    const floatx4 z4 = {0.f, 0.f, 0.f, 0.f};

    __syncthreads();   // the only barrier: staged+split chunk visible to all

#pragma unroll 4
    for (int ct = 0; ct < NCT; ++ct) {
        half8 bh = lds[(0 * 4 + quad) * KCHUNK + ct * 16 + lc];
        half8 bm = lds[(1 * 4 + quad) * KCHUNK + ct * 16 + lc];
        const int kk = kbase + ct * 16 + lc;
#pragma unroll
        for (int qt = 0; qt < 4; ++qt) {
            floatx4 a0 = __builtin_amdgcn_mfma_f32_16x16x32_f16(ah[qt], bh, z4, 0, 0, 0);
            floatx4 a1 = __builtin_amdgcn_mfma_f32_16x16x32_f16(ah[qt], bm, z4, 0, 0, 0);
            a1 = __builtin_amdgcn_mfma_f32_16x16x32_f16(am[qt], bh, a1, 0, 0, 0);
#pragma unroll
            for (int r = 0; r < 4; ++r) {
                float d = fmaf(a1[r], 0x1p-12f, a0[r]);
                if (d > best[qt * 4 + r]) { best[qt * 4 + r] = d; bk[qt * 4 + r] = kk; }
            }
        }
    }

    // ---- epilogue: pack (dot,k), reduce over 16 cols, plain store per row ----
#pragma unroll
    for (int i = 0; i < 16; ++i) {
        unsigned ub = __float_as_uint(best[i]);
        ub = (ub & 0x80000000u) ? ~ub : (ub | 0x80000000u);
        unsigned long long key = ((unsigned long long)ub << 32) | (unsigned)(~bk[i]);
#pragma unroll
        for (int msk = 1; msk <= 8; msk <<= 1) {
            unsigned long long o = __shfl_xor(key, msk, 64);
            key = (o > key) ? o : key;
        }
        if (lc == 0) {
            int qt = i >> 2, r = i & 3;
            int q = qbase + qt * 16 + quad * 4 + r;   // C row = quad*4 + reg
            keys16[kc * NQ + q] = key;                // block owns this slot
        }
    }
}

// ---------------------------------------------------------------------------
// K2: finalize. Per query: max over the 16 per-chunk keys (coalesced 128 B;
// max = best dot, tie -> smallest idx; dots bitwise-comparable across chunks
// since A/B frags are kc-independent), ONE row gather + local normalize,
// histogram, straight-through out, loss. Last-done block computes scalars.
// ---------------------------------------------------------------------------
__global__ __launch_bounds__(256) void finalize_kernel(const float* __restrict__ z,
                                                       const float* __restrict__ e,
                                                       const unsigned long long* __restrict__ keys16,
                                                       unsigned* __restrict__ usage,
                                                       float* __restrict__ loss_acc,
                                                       unsigned* __restrict__ done_ctr,
                                                       float* __restrict__ out) {
    int n = blockIdx.x * 256 + threadIdx.x;        // 0..NQ-1
    int b  = n >> 10;
    int hw = n & 1023;
    const float* zb = z + b * (DIM * 1024) + hw;

    float q[DIM];
    float ss = 0.f;
#pragma unroll
    for (int d = 0; d < DIM; ++d) {
        q[d] = zb[d * 1024];
        ss = fmaf(q[d], q[d], ss);
    }
    float inv = 1.f / fmaxf(sqrtf(ss), 1e-12f);
#pragma unroll
    for (int d = 0; d < DIM; ++d) q[d] *= inv;

    unsigned long long bestkey = 0ull;
#pragma unroll
    for (int c = 0; c < KSPL; ++c) {
        unsigned long long kk = keys16[c * NQ + n];
        bestkey = (kk > bestkey) ? kk : bestkey;
    }
    int idx = (int)(~(unsigned)(bestkey & 0xFFFFFFFFull));

    atomicAdd(&usage[idx], 1u);

    // gather winner row, normalize locally, write straight-through + loss
    float wv[DIM];
    float ss2 = 0.f;
    const float4* er = (const float4*)(e + idx * DIM);
#pragma unroll
    for (int d8 = 0; d8 < 8; ++d8) {
        float4 t4 = er[d8];
        wv[d8*4+0] = t4.x; wv[d8*4+1] = t4.y; wv[d8*4+2] = t4.z; wv[d8*4+3] = t4.w;
        ss2 += t4.x*t4.x + t4.y*t4.y + t4.z*t4.z + t4.w*t4.w;
    }
    float inv2 = 1.f / fmaxf(sqrtf(ss2), 1e-12f);

    float lsum = 0.f;
    float* outb = out + b * (DIM * 1024) + hw;
#pragma unroll
    for (int d = 0; d < DIM; ++d) {
        float zq = wv[d] * inv2;
        float diff = zq - q[d];
        lsum = fmaf(diff, diff, lsum);
        outb[d * 1024] = q[d] + (zq - q[d]);   // faithful to zn + sg(z_q - zn)
    }
    out[IDX_OFF + n] = (float)idx;

#pragma unroll
    for (int off = 32; off > 0; off >>= 1)
        lsum += __shfl_down(lsum, off, 64);
    if ((threadIdx.x & 63) == 0)
        atomicAdd(loss_acc, lsum);

    // ---- last-done block computes the scalars ----
    __shared__ unsigned lastflag;
    __syncthreads();
    if (threadIdx.x == 0) {
        __threadfence();
        unsigned prev = __hip_atomic_fetch_add(done_ctr, 1u, __ATOMIC_ACQ_REL,
                                               __HIP_MEMORY_SCOPE_AGENT);
        lastflag = (prev == gridDim.x - 1) ? 1u : 0u;
    }
    __syncthreads();
    if (lastflag) {
        __shared__ double sm[256];
        int t = threadIdx.x;
        double local = 0.0;
        const float denom = 32768.8192f;   // sum(usage)+K*eps; sum(usage)==NQ
        for (int k = t; k < N_EMBED; k += 256) {
            unsigned c = __hip_atomic_load(&usage[k], __ATOMIC_RELAXED,
                                           __HIP_MEMORY_SCOPE_AGENT);
            float p = ((float)c + 1e-4f) / denom;
            local += (double)(-(p * logf(p)));
        }
        sm[t] = local;
        __syncthreads();
        for (int s = 128; s > 0; s >>= 1) {
            if (t < s) sm[t] += sm[t + s];
            __syncthreads();
        }
        if (t == 0) {
            float la = __hip_atomic_load(loss_acc, __ATOMIC_RELAXED,
                                         __HIP_MEMORY_SCOPE_AGENT);
            out[LOSS_OFF] = (float)(1.25 * (double)la / 32768.0);  // (beta+1)*mean
            out[ENT_OFF]  = (float)sm[0];
        }
    }
}

// ---------------------------------------------------------------------------
extern "C" void kernel_launch(void* const* d_in, const int* in_sizes, int n_in,
                              void* d_out, int out_size, void* d_ws, size_t ws_size,
                              hipStream_t stream) {
    const float* z   = (const float*)d_in[0];   // (32, 32, 32, 32) bchw
    const float* emb = (const float*)d_in[1];   // (8192, 32)
    float* out = (float*)d_out;

    char* ws = (char*)d_ws;
    unsigned long long* keys16 = (unsigned long long*)ws;                    // 4 MiB @ 0
    unsigned* usage            = (unsigned*)(ws + (4 << 20));                // 32 KiB
    float* loss_acc            = (float*)(ws + (4 << 20) + 32768);
    unsigned* done_ctr         = (unsigned*)(ws + (4 << 20) + 32768 + 4);

    score_kernel<<<NQG * KSPL, 512, 0, stream>>>(z, emb, keys16, usage,
                                                 loss_acc, done_ctr);
    finalize_kernel<<<NQ / 256, 256, 0, stream>>>(z, emb, keys16, usage,
                                                  loss_acc, done_ctr, out);
}